// Round 5
// baseline (14305.679 us; speedup 1.0000x reference)
//
#include <hip/hip_runtime.h>
#include <hip/hip_bf16.h>

// Problem constants (fixed by setup_inputs)
#define BB 32
#define NN 64
#define TT 11
#define FF 4
#define KK 2
#define EE 4032      // N*(N-1)
#define NSTEP 10

typedef __bf16 bf16x8 __attribute__((ext_vector_type(8)));
typedef float  f32x4  __attribute__((ext_vector_type(4)));

#define LDK 136      // K-chunk tile row stride (128 + 8 pad) -> same +4-bank step as verified 264

// LDS byte offsets (single dynamic allocation, 157696 B total)
#define OFF_AH  0                        // A_hi [128][LDK] bf16 = 34816
#define OFF_AL  34816                    // A_lo
#define OFF_BH  69632                    // B_hi [128][LDK] bf16
#define OFF_BL  104448                   // B_lo
#define OFF_W1F 139264                   // W1 (this k) f32 [8][256] = 8192
#define OFF_Y   147456                   // y [64][4] f32 = 1024
#define OFF_VB  148480                   // b1 + recv part [2 ri][256] f32 = 2048
#define OFF_WGT 150528                   // edge weights [2 k][128] f32 = 1024
#define OFF_AGG 151552                   // agg [2 ri][256] f32 = 2048
#define OFF_P1  153600                   // MLP hidden [2][256] f32 = 2048
#define OFF_P2  155648                   // MLP hidden [2][256] f32 = 2048
#define SMEM_BYTES 157696                // < 160 KiB

__device__ __forceinline__ float scrub(float v) {
    return fminf(fmaxf(v, -3.0e4f), 3.0e4f);   // inactive when correct (|x| <~ 600)
}

// Dtype detector (round-3/4 proved the f32 branch is live; kept for robustness)
__device__ __forceinline__ bool detect_bf16(const void* tsp) {
    return ((float)((const __bf16*)tsp)[2]) == 2.0f;
}
__device__ __forceinline__ float ldf(const void* p, long long i, bool bf) {
    return bf ? (float)((const __bf16*)p)[i] : ((const float*)p)[i];
}
__device__ __forceinline__ float load_dt(const void* tsp, const void* scp, int step, bool bf) {
    float t0 = ldf(tsp, step, bf), t1 = ldf(tsp, step + 1, bf);
    int w = ((const int*)scp)[0];
    float scl;
    if (w > 0 && w < 1000000) scl = (float)w;
    else {
        float f = __int_as_float(w);
        if (f > 0.5f && f < 1.0e6f) scl = f;
        else {
            union { unsigned u; float f2; } cv;
            cv.u = ((unsigned)w & 0xFFFFu) << 16;
            scl = (cv.f2 > 0.5f && cv.f2 < 1.0e6f) ? cv.f2 : 10.0f;
        }
    }
    return (t1 - t0) / scl;
}

// One RK4 stage: k_{stage+1} = f(y_stage) for 2 receivers x 1 batch per block.
// Edge-GEMM uses split-bf16 (hi/lo) MFMA: A*B = Ah*Bh + Ah*Bl + Al*Bh  (~f32 precision).
__global__ __launch_bounds__(256, 1)
void stage_kernel(int stage, int step,
    const void* __restrict__ edges, const void* __restrict__ W1g,
    const void* __restrict__ b1g,
    const __bf16* __restrict__ W2Th, const __bf16* __restrict__ W2Tl,
    const void* __restrict__ b2g,  const void* __restrict__ Wo1,
    const void* __restrict__ bo1,  const void* __restrict__ Wo2,
    const void* __restrict__ bo2,  const void* __restrict__ Wo3,
    const void* __restrict__ bo3,  const void* __restrict__ tsp,
    const void* __restrict__ scp,
    const float* __restrict__ xcur,  const float* __restrict__ kprev,
    float* __restrict__ kout,
    const float* __restrict__ k1b,   const float* __restrict__ k2b,
    const float* __restrict__ k3b,
    float* __restrict__ xnext, float* __restrict__ outp)
{
    extern __shared__ char smem[];
    __bf16* smAh  = (__bf16*)(smem + OFF_AH);
    __bf16* smAl  = (__bf16*)(smem + OFF_AL);
    __bf16* smBh  = (__bf16*)(smem + OFF_BH);
    __bf16* smBl  = (__bf16*)(smem + OFF_BL);
    float*  smW1f = (float*)(smem + OFF_W1F);
    float*  smY   = (float*)(smem + OFF_Y);
    float*  smVB  = (float*)(smem + OFF_VB);
    float*  smWgt = (float*)(smem + OFF_WGT);
    float*  smAgg = (float*)(smem + OFF_AGG);
    float*  smP1  = (float*)(smem + OFF_P1);
    float*  smP2  = (float*)(smem + OFF_P2);

    const int tid = threadIdx.x;
    const int b   = blockIdx.x >> 5;
    const int rg  = blockIdx.x & 31;
    const int r0  = rg * 2;

    const bool bfm = detect_bf16(tsp);
    const float dt = load_dt(tsp, scp, step, bfm);
    const float cc = (stage == 0) ? 0.0f : ((stage == 3) ? 1.0f : 0.5f);

    // ---- P0: y, edge weights, zero agg ----
    {
        int gi = (b * NN) * FF + tid;           // tid = n*4+f
        float y = xcur[gi];
        if (stage != 0) y += cc * dt * kprev[gi];
        smY[tid] = scrub(y);
    }
    {
        int k = tid >> 7, m = tid & 127;
        int ri = m >> 6, jj = m & 63, r = r0 + ri;
        float w = 0.0f;
        if (jj < 63) w = ldf(edges, ((long long)b * EE + r * 63 + jj) * KK + k, bfm);
        smWgt[tid] = w;
    }
    smAgg[tid] = 0.0f; smAgg[tid + 256] = 0.0f;

    const int lane = tid & 63;
    const int wave = tid >> 6;
    const int wm   = wave >> 1;   // receiver (row) half
    const int wn   = wave & 1;    // column half within 128-col o-slab
    const int ln15 = lane & 15;
    const int lg   = lane >> 4;   // 0..3

    for (int k = 0; k < KK; ++k) {
        __syncthreads();          // y/wgt ready (k=0); prior-k readers of W1f done (k=1)
        // ---- W1 (this k) -> f32 LDS ----
        for (int i = tid; i < 2048; i += 256)
            smW1f[i] = ldf(W1g, (long long)k * 2048 + i, bfm);
        __syncthreads();
        // ---- vb[ri][h] = b1 + sum_f y[recv]*W1_recv  (f32 exact) ----
        for (int i = tid; i < 512; i += 256) {
            int ri = i >> 8, h = i & 255;
            float acc = ldf(b1g, k * 256 + h, bfm);
            #pragma unroll
            for (int f = 0; f < 4; ++f)
                acc += smY[(r0 + ri) * 4 + f] * smW1f[(4 + f) * 256 + h];
            smVB[i] = acc;
        }

        f32x4 acc[2][4][4];
        #pragma unroll
        for (int os = 0; os < 2; ++os)
            #pragma unroll
            for (int mi = 0; mi < 4; ++mi)
                #pragma unroll
                for (int ni = 0; ni < 4; ++ni)
                    acc[os][mi][ni] = (f32x4){0.f, 0.f, 0.f, 0.f};

        for (int kc = 0; kc < 2; ++kc) {
            __syncthreads();      // vb ready (kc=0) / prior MFMA done reading A (kc=1)
            // ---- build A hi/lo for K-chunk kc: rows = ri*64+jj (63,127 pad) ----
            for (int it = 0; it < 8; ++it) {
                int flat = it * 256 + tid;
                int m = flat >> 4, cg = flat & 15, h0 = cg * 8;
                int ri = m >> 6, jj = m & 63, r = r0 + ri;
                bf16x8 hv, lv;
                #pragma unroll
                for (int e = 0; e < 8; ++e) { hv[e] = (__bf16)0.0f; lv[e] = (__bf16)0.0f; }
                if (jj < 63) {
                    int s = jj + (jj >= r ? 1 : 0);
                    float y0 = smY[s*4+0], y1 = smY[s*4+1], y2 = smY[s*4+2], y3 = smY[s*4+3];
                    #pragma unroll
                    for (int e = 0; e < 8; ++e) {
                        int h = kc * 128 + h0 + e;
                        float v = smVB[ri * 256 + h]
                                + y0 * smW1f[0*256 + h] + y1 * smW1f[1*256 + h]
                                + y2 * smW1f[2*256 + h] + y3 * smW1f[3*256 + h];
                        v = fmaxf(v, 0.0f);
                        __bf16 hb = (__bf16)v;
                        hv[e] = hb;
                        lv[e] = (__bf16)(v - (float)hb);
                    }
                }
                *(bf16x8*)(smAh + m * LDK + h0) = hv;
                *(bf16x8*)(smAl + m * LDK + h0) = lv;
            }

            for (int os = 0; os < 2; ++os) {
                // ---- stage B hi/lo: rows o in [os*128, +128), cols kc*128.. ----
                for (int it = 0; it < 8; ++it) {
                    int flat = it * 256 + tid;
                    int row = flat >> 4, cg = flat & 15;
                    long long idx = ((long long)(k * 256 + os * 128 + row)) * 256 + kc * 128 + cg * 8;
                    *(uint4*)(smBh + row * LDK + cg * 8) = *(const uint4*)(W2Th + idx);
                    *(uint4*)(smBl + row * LDK + cg * 8) = *(const uint4*)(W2Tl + idx);
                }
                __syncthreads();   // A + B visible

                #pragma unroll
                for (int ks = 0; ks < 4; ++ks) {
                    int kko = ks * 32 + lg * 8;
                    bf16x8 ah[4], al[4], bh[4], bl[4];
                    #pragma unroll
                    for (int mi = 0; mi < 4; ++mi) {
                        ah[mi] = *(const bf16x8*)(smAh + (wm*64 + mi*16 + ln15) * LDK + kko);
                        al[mi] = *(const bf16x8*)(smAl + (wm*64 + mi*16 + ln15) * LDK + kko);
                    }
                    #pragma unroll
                    for (int ni = 0; ni < 4; ++ni) {
                        bh[ni] = *(const bf16x8*)(smBh + (wn*64 + ni*16 + ln15) * LDK + kko);
                        bl[ni] = *(const bf16x8*)(smBl + (wn*64 + ni*16 + ln15) * LDK + kko);
                    }
                    #pragma unroll
                    for (int mi = 0; mi < 4; ++mi)
                        #pragma unroll
                        for (int ni = 0; ni < 4; ++ni) {
                            acc[os][mi][ni] = __builtin_amdgcn_mfma_f32_16x16x32_bf16(
                                ah[mi], bh[ni], acc[os][mi][ni], 0, 0, 0);
                            acc[os][mi][ni] = __builtin_amdgcn_mfma_f32_16x16x32_bf16(
                                ah[mi], bl[ni], acc[os][mi][ni], 0, 0, 0);
                            acc[os][mi][ni] = __builtin_amdgcn_mfma_f32_16x16x32_bf16(
                                al[mi], bh[ni], acc[os][mi][ni], 0, 0, 0);
                        }
                }
                __syncthreads();   // reads done before next B stage / A rebuild
            }
        }

        // ---- epilogue: relu(+b2)*edge_w, reduce rows -> agg[wm][o] ----
        for (int os = 0; os < 2; ++os) {
            float bv[4], rsum[4];
            #pragma unroll
            for (int ni = 0; ni < 4; ++ni) {
                int o = os*128 + wn*64 + ni*16 + ln15;
                bv[ni] = ldf(b2g, k * 256 + o, bfm);
                rsum[ni] = 0.0f;
            }
            #pragma unroll
            for (int mi = 0; mi < 4; ++mi) {
                #pragma unroll
                for (int rr = 0; rr < 4; ++rr) {
                    // C/D: col = lane&15, row = (lane>>4)*4 + rr  [m89/m91]
                    float w = smWgt[k*128 + wm*64 + mi*16 + lg*4 + rr];
                    #pragma unroll
                    for (int ni = 0; ni < 4; ++ni)
                        rsum[ni] += fmaxf(acc[os][mi][ni][rr] + bv[ni], 0.0f) * w;
                }
            }
            #pragma unroll
            for (int ni = 0; ni < 4; ++ni) {
                rsum[ni] += __shfl_xor(rsum[ni], 16, 64);
                rsum[ni] += __shfl_xor(rsum[ni], 32, 64);
            }
            if (lane < 16) {
                #pragma unroll
                for (int ni = 0; ni < 4; ++ni) {
                    int o = os*128 + wn*64 + ni*16 + ln15;
                    smAgg[wm * 256 + o] += rsum[ni];   // unique (wave,o) writer
                }
            }
        }
    }
    __syncthreads();

    // ---- P2: node MLP (f32 exact) for receivers r0, r0+1 ----
    {
        int c = tid;
        float a0 = ldf(bo1, c, bfm), a1 = a0;
        #pragma unroll
        for (int f = 0; f < 4; ++f) {
            float wv = ldf(Wo1, f * 256 + c, bfm);
            a0 += smY[r0 * 4 + f] * wv;
            a1 += smY[(r0 + 1) * 4 + f] * wv;
        }
        for (int h = 0; h < 256; ++h) {
            float wv = ldf(Wo1, (4 + h) * 256 + c, bfm);
            a0 += smAgg[h] * wv;
            a1 += smAgg[256 + h] * wv;
        }
        smP1[c] = fmaxf(a0, 0.0f);
        smP1[256 + c] = fmaxf(a1, 0.0f);
    }
    __syncthreads();
    {
        int c = tid;
        float a0 = ldf(bo2, c, bfm), a1 = a0;
        for (int h = 0; h < 256; ++h) {
            float wv = ldf(Wo2, h * 256 + c, bfm);
            a0 += smP1[h] * wv;
            a1 += smP1[256 + h] * wv;
        }
        smP2[c] = fmaxf(a0, 0.0f);
        smP2[256 + c] = fmaxf(a1, 0.0f);
    }
    __syncthreads();
    if (tid < 8) {
        int ri = tid >> 2, f = tid & 3, r = r0 + ri;
        float acc = ldf(bo3, f, bfm);
        for (int h = 0; h < 256; ++h)
            acc += smP2[ri * 256 + h] * ldf(Wo3, h * 4 + f, bfm);
        float knew = scrub(smY[r * 4 + f] + acc);    // f(y) = y + p
        int gi = (b * NN + r) * FF + f;
        if (stage < 3) {
            kout[gi] = knew;
        } else {
            float xn = scrub(xcur[gi] + (dt * (1.0f / 6.0f)) *
                       (k1b[gi] + 2.0f * k2b[gi] + 2.0f * k3b[gi] + knew));
            xnext[gi] = xn;
            outp[((b * NN + r) * NSTEP + step) * FF + f] = xn;   // f32 output
        }
    }
}

__global__ void transpose_w2(const void* __restrict__ W2,
                             __bf16* __restrict__ W2Th, __bf16* __restrict__ W2Tl,
                             const void* __restrict__ tsp)
{
    const bool bfm = detect_bf16(tsp);
    int k = blockIdx.x >> 8, o = blockIdx.x & 255, h = threadIdx.x;
    float v = ldf(W2, (long long)(k * 256 + h) * 256 + o, bfm);
    __bf16 hi = (__bf16)v;
    long long di = (long long)(k * 256 + o) * 256 + h;
    W2Th[di] = hi;
    W2Tl[di] = (__bf16)(v - (float)hi);
}

__global__ void init_x(const void* __restrict__ inp, float* __restrict__ x0,
                       const void* __restrict__ tsp)
{
    const bool bfm = detect_bf16(tsp);
    int i = blockIdx.x * 256 + threadIdx.x;   // i = (b*64+n)*4+f
    if (i < BB * NN * FF) {
        int f = i & 3, bn = i >> 2;
        x0[i] = scrub(ldf(inp, (long long)(bn * TT) * FF + f, bfm));  // inputs[b][n][0][f]
    }
}

static int find_input(const int* in_sizes, int n_in, int want, unsigned char* used, int dflt) {
    if (dflt >= 0 && dflt < n_in && in_sizes[dflt] == want && !used[dflt]) { used[dflt] = 1; return dflt; }
    for (int i = 0; i < n_in; ++i)
        if (!used[i] && in_sizes[i] == want) { used[i] = 1; return i; }
    return dflt;
}

extern "C" void kernel_launch(void* const* d_in, const int* in_sizes, int n_in,
                              void* d_out, int out_size, void* d_ws, size_t ws_size,
                              hipStream_t stream)
{
    unsigned char used[64] = {0};
    int iInp = find_input(in_sizes, n_in, BB*NN*TT*FF, used, 0);
    int iEdg = find_input(in_sizes, n_in, BB*EE*KK,    used, 1);
    (void)find_input(in_sizes, n_in, EE*NN, used, 2);              // rel_rec (unused)
    (void)find_input(in_sizes, n_in, EE*NN, used, 3);              // rel_send (unused)
    int iW1  = find_input(in_sizes, n_in, KK*8*256,  used, 4);
    int ib1  = find_input(in_sizes, n_in, KK*256,    used, 5);
    int iW2  = find_input(in_sizes, n_in, KK*256*256,used, 6);
    int ib2  = find_input(in_sizes, n_in, KK*256,    used, 7);
    int iWo1 = find_input(in_sizes, n_in, 260*256,   used, 8);
    int ibo1 = find_input(in_sizes, n_in, 256,       used, 9);
    int iWo2 = find_input(in_sizes, n_in, 256*256,   used, 10);
    int ibo2 = find_input(in_sizes, n_in, 256,       used, 11);
    int iWo3 = find_input(in_sizes, n_in, 256*4,     used, 12);
    int ibo3 = find_input(in_sizes, n_in, 4,         used, 13);
    int iTs  = find_input(in_sizes, n_in, TT,        used, 14);
    (void)find_input(in_sizes, n_in, 1, used, 15);                 // pred_steps
    int iSc  = find_input(in_sizes, n_in, 1,         used, 16);    // scale

    const void* inputs = d_in[iInp];
    const void* edges  = d_in[iEdg];
    const void* W1  = d_in[iW1];
    const void* b1  = d_in[ib1];
    const void* W2  = d_in[iW2];
    const void* b2  = d_in[ib2];
    const void* Wo1 = d_in[iWo1];
    const void* bo1 = d_in[ibo1];
    const void* Wo2 = d_in[iWo2];
    const void* bo2 = d_in[ibo2];
    const void* Wo3 = d_in[iWo3];
    const void* bo3 = d_in[ibo3];
    const void* tsp = d_in[iTs];
    const void* scp = d_in[iSc];

    char* ws = (char*)d_ws;
    __bf16* W2Th = (__bf16*)ws;                        // 262144 B
    __bf16* W2Tl = (__bf16*)(ws + 262144);             // 262144 B
    float* xA = (float*)(ws + 524288);
    float* xB = (float*)(ws + 524288 + 1 * 32768);
    float* k1 = (float*)(ws + 524288 + 2 * 32768);
    float* k2 = (float*)(ws + 524288 + 3 * 32768);
    float* k3 = (float*)(ws + 524288 + 4 * 32768);

    float* outp = (float*)d_out;   // f32 output

    (void)hipFuncSetAttribute((const void*)stage_kernel,
        hipFuncAttributeMaxDynamicSharedMemorySize, SMEM_BYTES);

    transpose_w2<<<dim3(512), dim3(256), 0, stream>>>(W2, W2Th, W2Tl, tsp);
    init_x<<<dim3(32), dim3(256), 0, stream>>>(inputs, xA, tsp);

    float* xc = xA;
    float* xn = xB;
    for (int step = 0; step < NSTEP; ++step) {
        stage_kernel<<<dim3(1024), dim3(256), SMEM_BYTES, stream>>>(0, step,
            edges, W1, b1, W2Th, W2Tl, b2, Wo1, bo1, Wo2, bo2, Wo3, bo3, tsp, scp,
            xc, xc, k1, k1, k2, k3, xn, outp);
        stage_kernel<<<dim3(1024), dim3(256), SMEM_BYTES, stream>>>(1, step,
            edges, W1, b1, W2Th, W2Tl, b2, Wo1, bo1, Wo2, bo2, Wo3, bo3, tsp, scp,
            xc, k1, k2, k1, k2, k3, xn, outp);
        stage_kernel<<<dim3(1024), dim3(256), SMEM_BYTES, stream>>>(2, step,
            edges, W1, b1, W2Th, W2Tl, b2, Wo1, bo1, Wo2, bo2, Wo3, bo3, tsp, scp,
            xc, k2, k3, k1, k2, k3, xn, outp);
        stage_kernel<<<dim3(1024), dim3(256), SMEM_BYTES, stream>>>(3, step,
            edges, W1, b1, W2Th, W2Tl, b2, Wo1, bo1, Wo2, bo2, Wo3, bo3, tsp, scp,
            xc, k3, k3 /*unused*/, k1, k2, k3, xn, outp);
        float* t = xc; xc = xn; xn = t;
    }
}

// Round 6
// 6208.351 us; speedup vs baseline: 2.3043x; 2.3043x over previous
//
#include <hip/hip_runtime.h>

// Problem constants (fixed by setup_inputs)
#define BB 32
#define NN 64
#define TT 11
#define FF 4
#define KK 2
#define EE 4032      // N*(N-1)
#define NSTEP 10

typedef _Float16 f16x8 __attribute__((ext_vector_type(8)));
typedef float    f32x4v __attribute__((ext_vector_type(4)));

#define LDA 264      // f16 row stride: 256 + 8 pad -> conflict-minimum b128 phases (row=528B, 132 dw, %32=4)

// LDS byte offsets (single dynamic allocation)
#define OFF_A   0                       // A tile [128][LDA] f16 = 67584
#define OFF_B   67584                   // B slab [128][LDA] f16 = 67584
#define OFF_W1F 135168                  // W1 (this k) f32 [8][256] = 8192
#define OFF_Y   143360                  // y [64][4] f32 = 1024
#define OFF_VB  144384                  // b1 + recv part [2 ri][256] f32 = 2048
#define OFF_WGT 146432                  // edge weights [2 k][128] f32 = 1024
#define OFF_AGG 147456                  // agg [2 ri][256] f32 = 2048
#define OFF_P1  149504                  // MLP hidden [2][256] f32 = 2048
#define OFF_P2  151552                  // MLP hidden [2][256] f32 = 2048
#define SMEM_BYTES 153600               // < 160 KiB

__device__ __forceinline__ float scrub(float v) {
    return fminf(fmaxf(v, -3.0e4f), 3.0e4f);   // inactive when correct (|x| <~ 600)
}

__device__ __forceinline__ float load_dt(const float* ts, const void* scp, int step) {
    float t0 = ts[step], t1 = ts[step + 1];
    int w = ((const int*)scp)[0];
    float scl;
    if (w > 0 && w < 1000000) scl = (float)w;            // int32 (live path)
    else {
        float f = __int_as_float(w);
        scl = (f > 0.5f && f < 1.0e6f) ? f : 10.0f;
    }
    return (t1 - t0) / scl;
}

// One RK4 stage: k_{stage+1} = f(y_stage) for 2 receivers x 1 batch per block.
// Edge-GEMM: f16 MFMA (single product; W1-layer f32-exact; f32 accumulate).
__global__ __launch_bounds__(256, 1)
void stage_kernel(int stage, int step,
    const float* __restrict__ edges, const float* __restrict__ W1g,
    const float* __restrict__ b1g,   const _Float16* __restrict__ W2T,
    const float* __restrict__ b2g,   const float* __restrict__ Wo1,
    const float* __restrict__ bo1,   const float* __restrict__ Wo2,
    const float* __restrict__ bo2,   const float* __restrict__ Wo3,
    const float* __restrict__ bo3,   const float* __restrict__ ts,
    const void* __restrict__ scp,
    const float* __restrict__ xcur,  const float* __restrict__ kprev,
    float* __restrict__ kout,
    const float* __restrict__ k1b,   const float* __restrict__ k2b,
    const float* __restrict__ k3b,
    float* __restrict__ xnext, float* __restrict__ outp)
{
    extern __shared__ char smem[];
    _Float16* smA   = (_Float16*)(smem + OFF_A);
    _Float16* smB   = (_Float16*)(smem + OFF_B);
    float*  smW1f = (float*)(smem + OFF_W1F);
    float*  smY   = (float*)(smem + OFF_Y);
    float*  smVB  = (float*)(smem + OFF_VB);
    float*  smWgt = (float*)(smem + OFF_WGT);
    float*  smAgg = (float*)(smem + OFF_AGG);
    float*  smP1  = (float*)(smem + OFF_P1);
    float*  smP2  = (float*)(smem + OFF_P2);

    const int tid = threadIdx.x;
    const int b   = blockIdx.x >> 5;
    const int rg  = blockIdx.x & 31;
    const int r0  = rg * 2;

    const float dt = load_dt(ts, scp, step);
    const float cc = (stage == 0) ? 0.0f : ((stage == 3) ? 1.0f : 0.5f);

    // ---- P0: y, edge weights, zero agg ----
    {
        int gi = (b * NN) * FF + tid;           // tid = n*4+f
        float y = xcur[gi];
        if (stage != 0) y += cc * dt * kprev[gi];
        smY[tid] = scrub(y);
    }
    {
        int k = tid >> 7, m = tid & 127;
        int ri = m >> 6, jj = m & 63, r = r0 + ri;
        float w = 0.0f;
        if (jj < 63) w = edges[((size_t)b * EE + r * 63 + jj) * KK + k];
        smWgt[tid] = w;
    }
    smAgg[tid] = 0.0f; smAgg[tid + 256] = 0.0f;

    const int lane = tid & 63;
    const int wave = tid >> 6;
    const int wm   = wave >> 1;   // receiver (row) half of M
    const int wn   = wave & 1;    // column half within 128-col slab
    const int ln15 = lane & 15;
    const int lg   = lane >> 4;   // 0..3

    for (int k = 0; k < KK; ++k) {
        __syncthreads();          // P0/prev-k MFMA done; smA/smW1f safe
        // ---- W1 (this k) -> f32 LDS (vectorized) ----
        {
            const f32x4v* src = (const f32x4v*)(W1g + k * 2048);
            f32x4v* dst = (f32x4v*)smW1f;
            dst[tid] = src[tid];
            dst[tid + 256] = src[tid + 256];
        }
        __syncthreads();          // W1f ready
        // ---- vb[ri][h] = b1 + sum_f y[recv]*W1_recv  (f32 exact) ----
        for (int i = tid; i < 512; i += 256) {
            int ri = i >> 8, h = i & 255;
            float acc = b1g[k * 256 + h];
            #pragma unroll
            for (int f = 0; f < 4; ++f)
                acc += smY[(r0 + ri) * 4 + f] * smW1f[(4 + f) * 256 + h];
            smVB[i] = acc;
        }
        __syncthreads();          // vb ready
        // ---- build A: A[ri*64+jj][h] = relu(u_send + vb), f16; rows 63,127 pad ----
        for (int it = 0; it < 16; ++it) {
            int flat = it * 256 + tid;
            int m = flat >> 5, c8 = flat & 31, h0 = c8 * 8;
            int ri = m >> 6, jj = m & 63, r = r0 + ri;
            f16x8 pv;
            #pragma unroll
            for (int e = 0; e < 8; ++e) pv[e] = (_Float16)0.0f;
            if (jj < 63) {
                int s = jj + (jj >= r ? 1 : 0);
                float y0 = smY[s*4+0], y1 = smY[s*4+1], y2 = smY[s*4+2], y3 = smY[s*4+3];
                f32x4v vbA = *(const f32x4v*)(smVB + ri * 256 + h0);
                f32x4v vbB = *(const f32x4v*)(smVB + ri * 256 + h0 + 4);
                f32x4v w0A = *(const f32x4v*)(smW1f + 0*256 + h0);
                f32x4v w0B = *(const f32x4v*)(smW1f + 0*256 + h0 + 4);
                f32x4v w1A = *(const f32x4v*)(smW1f + 1*256 + h0);
                f32x4v w1B = *(const f32x4v*)(smW1f + 1*256 + h0 + 4);
                f32x4v w2A = *(const f32x4v*)(smW1f + 2*256 + h0);
                f32x4v w2B = *(const f32x4v*)(smW1f + 2*256 + h0 + 4);
                f32x4v w3A = *(const f32x4v*)(smW1f + 3*256 + h0);
                f32x4v w3B = *(const f32x4v*)(smW1f + 3*256 + h0 + 4);
                #pragma unroll
                for (int e = 0; e < 4; ++e) {
                    float vA = vbA[e] + y0*w0A[e] + y1*w1A[e] + y2*w2A[e] + y3*w3A[e];
                    float vB = vbB[e] + y0*w0B[e] + y1*w1B[e] + y2*w2B[e] + y3*w3B[e];
                    pv[e]     = (_Float16)fmaxf(vA, 0.0f);
                    pv[e + 4] = (_Float16)fmaxf(vB, 0.0f);
                }
            }
            *(f16x8*)(smA + m * LDA + h0) = pv;
        }

        for (int ns = 0; ns < 2; ++ns) {
            __syncthreads();  // A visible (ns=0) / prev MFMA done with smB (ns=1)
            // ---- stage B slab: rows = W2T[k][ns*128+row][:] (row = output o) ----
            for (int it = 0; it < 16; ++it) {
                int flat = it * 256 + tid;
                int row = flat >> 5, c8 = flat & 31;
                const uint4* src = (const uint4*)(W2T + ((size_t)(k * 256 + ns * 128 + row) * 256 + c8 * 8));
                *(uint4*)(smB + row * LDA + c8 * 8) = *src;
            }
            __syncthreads();

            // ---- 64x64 per wave: 4x4 subtiles of 16x16x32 f16 ----
            f32x4v acc[4][4];
            #pragma unroll
            for (int mi = 0; mi < 4; ++mi)
                #pragma unroll
                for (int ni = 0; ni < 4; ++ni)
                    acc[mi][ni] = (f32x4v){0.f, 0.f, 0.f, 0.f};

            for (int kk = 0; kk < 256; kk += 32) {
                f16x8 af[4], bfr[4];
                #pragma unroll
                for (int mi = 0; mi < 4; ++mi)
                    af[mi] = *(const f16x8*)(smA + (wm*64 + mi*16 + ln15) * LDA + kk + lg * 8);
                #pragma unroll
                for (int ni = 0; ni < 4; ++ni)
                    bfr[ni] = *(const f16x8*)(smB + (wn*64 + ni*16 + ln15) * LDA + kk + lg * 8);
                #pragma unroll
                for (int mi = 0; mi < 4; ++mi)
                    #pragma unroll
                    for (int ni = 0; ni < 4; ++ni)
                        acc[mi][ni] = __builtin_amdgcn_mfma_f32_16x16x32_f16(
                            af[mi], bfr[ni], acc[mi][ni], 0, 0, 0);
            }

            // ---- epilogue: relu(+b2)*edge_w, reduce rows -> agg[wm][o] ----
            float bv[4], rsum[4];
            #pragma unroll
            for (int ni = 0; ni < 4; ++ni) {
                int o = ns*128 + wn*64 + ni*16 + ln15;
                bv[ni] = b2g[k * 256 + o];
                rsum[ni] = 0.0f;
            }
            #pragma unroll
            for (int mi = 0; mi < 4; ++mi) {
                #pragma unroll
                for (int rr = 0; rr < 4; ++rr) {
                    // C/D: col = lane&15, row = (lane>>4)*4 + rr  [m89/m91]
                    float w = smWgt[k*128 + wm*64 + mi*16 + lg*4 + rr];
                    #pragma unroll
                    for (int ni = 0; ni < 4; ++ni)
                        rsum[ni] += fmaxf(acc[mi][ni][rr] + bv[ni], 0.0f) * w;
                }
            }
            #pragma unroll
            for (int ni = 0; ni < 4; ++ni) {
                rsum[ni] += __shfl_xor(rsum[ni], 16, 64);
                rsum[ni] += __shfl_xor(rsum[ni], 32, 64);
            }
            if (lane < 16) {
                #pragma unroll
                for (int ni = 0; ni < 4; ++ni) {
                    int o = ns*128 + wn*64 + ni*16 + ln15;
                    smAgg[wm * 256 + o] += rsum[ni];   // unique (wave,o) writer
                }
            }
        }
    }
    __syncthreads();

    // ---- P2: node MLP (f32 exact, branch-free pipelined loads) ----
    {
        int c = tid;
        float a0 = bo1[c], a1 = a0;
        #pragma unroll
        for (int f = 0; f < 4; ++f) {
            float wv = Wo1[f * 256 + c];
            a0 += smY[r0 * 4 + f] * wv;
            a1 += smY[(r0 + 1) * 4 + f] * wv;
        }
        const float* wp = Wo1 + 4 * 256 + c;
        #pragma unroll 8
        for (int h = 0; h < 256; ++h) {
            float wv = wp[h * 256];
            a0 += smAgg[h] * wv;
            a1 += smAgg[256 + h] * wv;
        }
        smP1[c] = fmaxf(a0, 0.0f);
        smP1[256 + c] = fmaxf(a1, 0.0f);
    }
    __syncthreads();
    {
        int c = tid;
        float a0 = bo2[c], a1 = a0;
        const float* wp = Wo2 + c;
        #pragma unroll 8
        for (int h = 0; h < 256; ++h) {
            float wv = wp[h * 256];
            a0 += smP1[h] * wv;
            a1 += smP1[256 + h] * wv;
        }
        smP2[c] = fmaxf(a0, 0.0f);
        smP2[256 + c] = fmaxf(a1, 0.0f);
    }
    __syncthreads();
    // ---- P3: last layer distributed over all 256 threads; shfl-reduce 32-lane groups ----
    {
        int ri = tid >> 7;            // 0/1
        int f  = (tid >> 5) & 3;
        int hs = tid & 31;
        float part = 0.0f;
        #pragma unroll
        for (int j = 0; j < 8; ++j) {
            int h = hs + j * 32;
            part += smP2[ri * 256 + h] * Wo3[h * 4 + f];
        }
        part += __shfl_xor(part, 16, 64);
        part += __shfl_xor(part, 8, 64);
        part += __shfl_xor(part, 4, 64);
        part += __shfl_xor(part, 2, 64);
        part += __shfl_xor(part, 1, 64);
        if (hs == 0) {
            int r = r0 + ri;
            float knew = scrub(smY[r * 4 + f] + bo3[f] + part);  // f(y) = y + p
            int gi = (b * NN + r) * FF + f;
            if (stage < 3) {
                kout[gi] = knew;
            } else {
                float xn = scrub(xcur[gi] + (dt * (1.0f / 6.0f)) *
                           (k1b[gi] + 2.0f * k2b[gi] + 2.0f * k3b[gi] + knew));
                xnext[gi] = xn;
                outp[((b * NN + r) * NSTEP + step) * FF + f] = xn;   // f32 output
            }
        }
    }
}

__global__ void transpose_w2(const float* __restrict__ W2, _Float16* __restrict__ W2T)
{
    int k = blockIdx.x >> 8, o = blockIdx.x & 255, h = threadIdx.x;
    W2T[(size_t)(k * 256 + o) * 256 + h] = (_Float16)W2[(size_t)(k * 256 + h) * 256 + o];
}

__global__ void init_x(const float* __restrict__ inp, float* __restrict__ x0)
{
    int i = blockIdx.x * 256 + threadIdx.x;   // i = (b*64+n)*4+f
    if (i < BB * NN * FF) {
        int f = i & 3, bn = i >> 2;
        x0[i] = scrub(inp[(size_t)(bn * TT) * FF + f]);   // inputs[b][n][0][f]
    }
}

static int find_input(const int* in_sizes, int n_in, int want, unsigned char* used, int dflt) {
    if (dflt >= 0 && dflt < n_in && in_sizes[dflt] == want && !used[dflt]) { used[dflt] = 1; return dflt; }
    for (int i = 0; i < n_in; ++i)
        if (!used[i] && in_sizes[i] == want) { used[i] = 1; return i; }
    return dflt;
}

extern "C" void kernel_launch(void* const* d_in, const int* in_sizes, int n_in,
                              void* d_out, int out_size, void* d_ws, size_t ws_size,
                              hipStream_t stream)
{
    unsigned char used[64] = {0};
    int iInp = find_input(in_sizes, n_in, BB*NN*TT*FF, used, 0);
    int iEdg = find_input(in_sizes, n_in, BB*EE*KK,    used, 1);
    (void)find_input(in_sizes, n_in, EE*NN, used, 2);              // rel_rec (unused)
    (void)find_input(in_sizes, n_in, EE*NN, used, 3);              // rel_send (unused)
    int iW1  = find_input(in_sizes, n_in, KK*8*256,  used, 4);
    int ib1  = find_input(in_sizes, n_in, KK*256,    used, 5);
    int iW2  = find_input(in_sizes, n_in, KK*256*256,used, 6);
    int ib2  = find_input(in_sizes, n_in, KK*256,    used, 7);
    int iWo1 = find_input(in_sizes, n_in, 260*256,   used, 8);
    int ibo1 = find_input(in_sizes, n_in, 256,       used, 9);
    int iWo2 = find_input(in_sizes, n_in, 256*256,   used, 10);
    int ibo2 = find_input(in_sizes, n_in, 256,       used, 11);
    int iWo3 = find_input(in_sizes, n_in, 256*4,     used, 12);
    int ibo3 = find_input(in_sizes, n_in, 4,         used, 13);
    int iTs  = find_input(in_sizes, n_in, TT,        used, 14);
    (void)find_input(in_sizes, n_in, 1, used, 15);                 // pred_steps
    int iSc  = find_input(in_sizes, n_in, 1,         used, 16);    // scale

    const float* inputs = (const float*)d_in[iInp];
    const float* edges  = (const float*)d_in[iEdg];
    const float* W1  = (const float*)d_in[iW1];
    const float* b1  = (const float*)d_in[ib1];
    const float* W2  = (const float*)d_in[iW2];
    const float* b2  = (const float*)d_in[ib2];
    const float* Wo1 = (const float*)d_in[iWo1];
    const float* bo1 = (const float*)d_in[ibo1];
    const float* Wo2 = (const float*)d_in[iWo2];
    const float* bo2 = (const float*)d_in[ibo2];
    const float* Wo3 = (const float*)d_in[iWo3];
    const float* bo3 = (const float*)d_in[ibo3];
    const float* ts  = (const float*)d_in[iTs];
    const void*  scp = d_in[iSc];

    char* ws = (char*)d_ws;
    _Float16* W2T = (_Float16*)ws;                     // 262144 B
    float* xA = (float*)(ws + 262144);
    float* xB = (float*)(ws + 262144 + 1 * 32768);
    float* k1 = (float*)(ws + 262144 + 2 * 32768);
    float* k2 = (float*)(ws + 262144 + 3 * 32768);
    float* k3 = (float*)(ws + 262144 + 4 * 32768);

    float* outp = (float*)d_out;   // f32 output

    (void)hipFuncSetAttribute((const void*)stage_kernel,
        hipFuncAttributeMaxDynamicSharedMemorySize, SMEM_BYTES);

    transpose_w2<<<dim3(512), dim3(256), 0, stream>>>(W2, W2T);
    init_x<<<dim3(32), dim3(256), 0, stream>>>(inputs, xA);

    float* xc = xA;
    float* xn = xB;
    for (int step = 0; step < NSTEP; ++step) {
        stage_kernel<<<dim3(1024), dim3(256), SMEM_BYTES, stream>>>(0, step,
            edges, W1, b1, W2T, b2, Wo1, bo1, Wo2, bo2, Wo3, bo3, ts, scp,
            xc, xc, k1, k1, k2, k3, xn, outp);
        stage_kernel<<<dim3(1024), dim3(256), SMEM_BYTES, stream>>>(1, step,
            edges, W1, b1, W2T, b2, Wo1, bo1, Wo2, bo2, Wo3, bo3, ts, scp,
            xc, k1, k2, k1, k2, k3, xn, outp);
        stage_kernel<<<dim3(1024), dim3(256), SMEM_BYTES, stream>>>(2, step,
            edges, W1, b1, W2T, b2, Wo1, bo1, Wo2, bo2, Wo3, bo3, ts, scp,
            xc, k2, k3, k1, k2, k3, xn, outp);
        stage_kernel<<<dim3(1024), dim3(256), SMEM_BYTES, stream>>>(3, step,
            edges, W1, b1, W2T, b2, Wo1, bo1, Wo2, bo2, Wo3, bo3, ts, scp,
            xc, k3, k3 /*unused*/, k1, k2, k3, xn, outp);
        float* t = xc; xc = xn; xn = t;
    }
}

// Round 7
// 3359.050 us; speedup vs baseline: 4.2588x; 1.8482x over previous
//
#include <hip/hip_runtime.h>

// Problem constants (fixed by setup_inputs)
#define BB 32
#define NN 64
#define TT 11
#define FF 4
#define KK 2
#define EE 4032      // N*(N-1)
#define NSTEP 10

typedef _Float16 f16x8 __attribute__((ext_vector_type(8)));
typedef float    f32x4v __attribute__((ext_vector_type(4)));

// LDS layout (fragment-major A, no B slab) — 79872 B total -> 2 blocks/CU
#define OFF_A    0        // A [8 mt][8 kc] chunks of 1 KiB (f16, fragment-major) = 65536
#define OFF_W1F  65536    // W1 (this k) f32 [8][256] = 8192   (union: P2 after GEMM)
#define OFF_Y    73728    // y [64][4] f32 = 1024
#define OFF_VB   74752    // b1 + recv part [2 ri][256] f32 = 2048 (union: P1)
#define OFF_WGT  76800    // edge weights [2 k][128] f32 = 1024
#define OFF_AGG  77824    // agg [2 ri][256] f32 = 2048
#define SMEM_BYTES 79872  // <= 81920 -> 2 blocks/CU

__device__ __forceinline__ float scrub(float v) {
    return fminf(fmaxf(v, -3.0e4f), 3.0e4f);   // inactive when correct (|x| <~ 600)
}

__device__ __forceinline__ float load_dt(const float* ts, const void* scp, int step) {
    float t0 = ts[step], t1 = ts[step + 1];
    int w = ((const int*)scp)[0];
    float scl;
    if (w > 0 && w < 1000000) scl = (float)w;            // int32 (live path)
    else {
        float f = __int_as_float(w);
        scl = (f > 0.5f && f < 1.0e6f) ? f : 10.0f;
    }
    return (t1 - t0) / scl;
}

// One RK4 stage: k_{stage+1} = f(y_stage) for 2 receivers x 1 batch per block.
// Edge-GEMM: f16 MFMA; A fragment-major in LDS (conflict-free); B fragments
// read directly from L2-resident pre-swizzled W2F (no LDS staging).
__global__ __launch_bounds__(256, 2)
void stage_kernel(int stage, int step,
    const float* __restrict__ edges, const float* __restrict__ W1g,
    const float* __restrict__ b1g,   const _Float16* __restrict__ W2F,
    const float* __restrict__ b2g,   const float* __restrict__ Wo1,
    const float* __restrict__ bo1,   const float* __restrict__ Wo2,
    const float* __restrict__ bo2,   const float* __restrict__ Wo3,
    const float* __restrict__ bo3,   const float* __restrict__ ts,
    const void* __restrict__ scp,
    const float* __restrict__ xcur,  const float* __restrict__ kprev,
    float* __restrict__ kout,
    const float* __restrict__ k1b,   const float* __restrict__ k2b,
    const float* __restrict__ k3b,
    float* __restrict__ xnext, float* __restrict__ outp)
{
    extern __shared__ char smem[];
    _Float16* smA   = (_Float16*)(smem + OFF_A);
    float*  smW1f = (float*)(smem + OFF_W1F);
    float*  smY   = (float*)(smem + OFF_Y);
    float*  smVB  = (float*)(smem + OFF_VB);
    float*  smWgt = (float*)(smem + OFF_WGT);
    float*  smAgg = (float*)(smem + OFF_AGG);
    float*  smP1  = (float*)(smem + OFF_VB);    // union: after GEMM, VB dead
    float*  smP2  = (float*)(smem + OFF_W1F);   // union: after GEMM, W1F dead

    const int tid = threadIdx.x;
    const int b   = blockIdx.x >> 5;
    const int rg  = blockIdx.x & 31;
    const int r0  = rg * 2;

    const float dt = load_dt(ts, scp, step);
    const float cc = (stage == 0) ? 0.0f : ((stage == 3) ? 1.0f : 0.5f);

    // ---- P0: y, edge weights, zero agg ----
    {
        int gi = (b * NN) * FF + tid;           // tid = n*4+f
        float y = xcur[gi];
        if (stage != 0) y += cc * dt * kprev[gi];
        smY[tid] = scrub(y);
    }
    {
        int k = tid >> 7, m = tid & 127;
        int ri = m >> 6, jj = m & 63, r = r0 + ri;
        float w = 0.0f;
        if (jj < 63) w = edges[((size_t)b * EE + r * 63 + jj) * KK + k];
        smWgt[tid] = w;
    }
    smAgg[tid] = 0.0f; smAgg[tid + 256] = 0.0f;

    const int lane = tid & 63;
    const int wave = tid >> 6;
    const int wm   = wave >> 1;   // receiver (row) half of M
    const int wn   = wave & 1;    // 64-col half within each 128-col ns-slab
    const int ln15 = lane & 15;
    const int lg   = lane >> 4;   // 0..3

    for (int k = 0; k < KK; ++k) {
        __syncthreads();          // P0 done (k=0) / prev-k MFMA+W1F reads done
        // ---- W1 (this k) -> f32 LDS ----
        {
            const f32x4v* src = (const f32x4v*)(W1g + k * 2048);
            f32x4v* dst = (f32x4v*)smW1f;
            dst[tid] = src[tid];
            dst[tid + 256] = src[tid + 256];
        }
        __syncthreads();          // W1f ready
        // ---- vb[ri][h] = b1 + sum_f y[recv]*W1_recv (f32 exact) ----
        for (int i = tid; i < 512; i += 256) {
            int ri = i >> 8, h = i & 255;
            float acc = b1g[k * 256 + h];
            #pragma unroll
            for (int f = 0; f < 4; ++f)
                acc += smY[(r0 + ri) * 4 + f] * smW1f[(4 + f) * 256 + h];
            smVB[i] = acc;
        }
        __syncthreads();          // vb ready
        // ---- build A (fragment-major): unit u -> chunk=u>>6, lane=u&63 ----
        for (int it = 0; it < 16; ++it) {
            int u = it * 256 + tid;
            int ch = u >> 6, l = u & 63;
            int mt = ch >> 3, kc = ch & 7;
            int m = mt * 16 + (l & 15);
            int h0 = kc * 32 + (l >> 4) * 8;
            int ri = m >> 6, jj = m & 63, r = r0 + ri;
            f16x8 pv;
            #pragma unroll
            for (int e = 0; e < 8; ++e) pv[e] = (_Float16)0.0f;
            if (jj < 63) {
                int s = jj + (jj >= r ? 1 : 0);
                float y0 = smY[s*4+0], y1 = smY[s*4+1], y2 = smY[s*4+2], y3 = smY[s*4+3];
                f32x4v vbA = *(const f32x4v*)(smVB + ri * 256 + h0);
                f32x4v vbB = *(const f32x4v*)(smVB + ri * 256 + h0 + 4);
                f32x4v w0A = *(const f32x4v*)(smW1f + 0*256 + h0);
                f32x4v w0B = *(const f32x4v*)(smW1f + 0*256 + h0 + 4);
                f32x4v w1A = *(const f32x4v*)(smW1f + 1*256 + h0);
                f32x4v w1B = *(const f32x4v*)(smW1f + 1*256 + h0 + 4);
                f32x4v w2A = *(const f32x4v*)(smW1f + 2*256 + h0);
                f32x4v w2B = *(const f32x4v*)(smW1f + 2*256 + h0 + 4);
                f32x4v w3A = *(const f32x4v*)(smW1f + 3*256 + h0);
                f32x4v w3B = *(const f32x4v*)(smW1f + 3*256 + h0 + 4);
                #pragma unroll
                for (int e = 0; e < 4; ++e) {
                    float vA = vbA[e] + y0*w0A[e] + y1*w1A[e] + y2*w2A[e] + y3*w3A[e];
                    float vB = vbB[e] + y0*w0B[e] + y1*w1B[e] + y2*w2B[e] + y3*w3B[e];
                    pv[e]     = (_Float16)fmaxf(vA, 0.0f);
                    pv[e + 4] = (_Float16)fmaxf(vB, 0.0f);
                }
            }
            *(f16x8*)(smA + (size_t)u * 8) = pv;   // coalesced, conflict-free
        }
        __syncthreads();          // A ready

        // ---- GEMM: two 128-col passes; B fragments straight from L2 ----
        for (int ns = 0; ns < 2; ++ns) {
            f32x4v acc[4][4];
            #pragma unroll
            for (int mi = 0; mi < 4; ++mi)
                #pragma unroll
                for (int ni = 0; ni < 4; ++ni)
                    acc[mi][ni] = (f32x4v){0.f, 0.f, 0.f, 0.f};

            const _Float16* bbase = W2F
                + ((size_t)((k * 16 + ns * 8 + wn * 4) * 8)) * 512 + lane * 8;
            #pragma unroll
            for (int kc = 0; kc < 8; ++kc) {
                f16x8 af[4], bfr[4];
                #pragma unroll
                for (int ni = 0; ni < 4; ++ni)
                    bfr[ni] = *(const f16x8*)(bbase + (size_t)(ni * 8 + kc) * 512);
                #pragma unroll
                for (int mi = 0; mi < 4; ++mi)
                    af[mi] = *(const f16x8*)(smA + (size_t)(((wm*4 + mi) * 8 + kc) << 9) + lane * 8);
                #pragma unroll
                for (int mi = 0; mi < 4; ++mi)
                    #pragma unroll
                    for (int ni = 0; ni < 4; ++ni)
                        acc[mi][ni] = __builtin_amdgcn_mfma_f32_16x16x32_f16(
                            af[mi], bfr[ni], acc[mi][ni], 0, 0, 0);
            }

            // ---- epilogue: relu(+b2)*edge_w, reduce rows -> agg[wm][o] ----
            float bv[4], rsum[4];
            #pragma unroll
            for (int ni = 0; ni < 4; ++ni) {
                int o = (ns*8 + wn*4 + ni) * 16 + ln15;
                bv[ni] = b2g[k * 256 + o];
                rsum[ni] = 0.0f;
            }
            #pragma unroll
            for (int mi = 0; mi < 4; ++mi) {
                #pragma unroll
                for (int rr = 0; rr < 4; ++rr) {
                    // C/D: col = lane&15, row = (lane>>4)*4 + rr  [m89/m91]
                    float w = smWgt[k*128 + wm*64 + mi*16 + lg*4 + rr];
                    #pragma unroll
                    for (int ni = 0; ni < 4; ++ni)
                        rsum[ni] += fmaxf(acc[mi][ni][rr] + bv[ni], 0.0f) * w;
                }
            }
            #pragma unroll
            for (int ni = 0; ni < 4; ++ni) {
                rsum[ni] += __shfl_xor(rsum[ni], 16, 64);
                rsum[ni] += __shfl_xor(rsum[ni], 32, 64);
            }
            if (lane < 16) {
                #pragma unroll
                for (int ni = 0; ni < 4; ++ni) {
                    int o = (ns*8 + wn*4 + ni) * 16 + ln15;
                    smAgg[wm * 256 + o] += rsum[ni];   // unique (wave,o) writer
                }
            }
        }
    }
    __syncthreads();   // agg complete; VB/W1F now dead -> P1/P2 reuse

    // ---- P2: node MLP (f32 exact) ----
    {
        int c = tid;
        float a0 = bo1[c], a1 = a0;
        #pragma unroll
        for (int f = 0; f < 4; ++f) {
            float wv = Wo1[f * 256 + c];
            a0 += smY[r0 * 4 + f] * wv;
            a1 += smY[(r0 + 1) * 4 + f] * wv;
        }
        const float* wp = Wo1 + 4 * 256 + c;
        #pragma unroll 8
        for (int h = 0; h < 256; ++h) {
            float wv = wp[h * 256];
            a0 += smAgg[h] * wv;
            a1 += smAgg[256 + h] * wv;
        }
        smP1[c] = fmaxf(a0, 0.0f);
        smP1[256 + c] = fmaxf(a1, 0.0f);
    }
    __syncthreads();
    {
        int c = tid;
        float a0 = bo2[c], a1 = a0;
        const float* wp = Wo2 + c;
        #pragma unroll 8
        for (int h = 0; h < 256; ++h) {
            float wv = wp[h * 256];
            a0 += smP1[h] * wv;
            a1 += smP1[256 + h] * wv;
        }
        smP2[c] = fmaxf(a0, 0.0f);
        smP2[256 + c] = fmaxf(a1, 0.0f);
    }
    __syncthreads();
    // ---- P3: last layer over all 256 threads; shfl-reduce 32-lane groups ----
    {
        int ri = tid >> 7;            // 0/1
        int f  = (tid >> 5) & 3;
        int hs = tid & 31;
        float part = 0.0f;
        #pragma unroll
        for (int j = 0; j < 8; ++j) {
            int h = hs + j * 32;
            part += smP2[ri * 256 + h] * Wo3[h * 4 + f];
        }
        part += __shfl_xor(part, 16, 64);
        part += __shfl_xor(part, 8, 64);
        part += __shfl_xor(part, 4, 64);
        part += __shfl_xor(part, 2, 64);
        part += __shfl_xor(part, 1, 64);
        if (hs == 0) {
            int r = r0 + ri;
            float knew = scrub(smY[r * 4 + f] + bo3[f] + part);  // f(y) = y + p
            int gi = (b * NN + r) * FF + f;
            if (stage < 3) {
                kout[gi] = knew;
            } else {
                float xn = scrub(xcur[gi] + (dt * (1.0f / 6.0f)) *
                           (k1b[gi] + 2.0f * k2b[gi] + 2.0f * k3b[gi] + knew));
                xnext[gi] = xn;
                outp[((b * NN + r) * NSTEP + step) * FF + f] = xn;   // f32 output
            }
        }
    }
}

// Pre-swizzle W2 -> fragment-major W2F: chunk (k,ot,kc) is 1 KiB; lane l holds
// B[o = ot*16 + (l&15)][h = kc*32 + (l>>4)*8 + e]  (= W2[k][h][o], f16)
__global__ void swizzle_w2(const float* __restrict__ W2, _Float16* __restrict__ W2F)
{
    int idx = blockIdx.x * 256 + threadIdx.x;       // 0 .. 131071
    int k   = idx >> 16;
    int rem = idx & 65535;
    int ch  = rem >> 9;
    int pos = rem & 511;
    int ot  = ch >> 3, kc = ch & 7;
    int l   = pos >> 3, e = pos & 7;
    int o   = ot * 16 + (l & 15);
    int h   = kc * 32 + (l >> 4) * 8 + e;
    W2F[idx] = (_Float16)W2[(size_t)(k * 256 + h) * 256 + o];
}

__global__ void init_x(const float* __restrict__ inp, float* __restrict__ x0)
{
    int i = blockIdx.x * 256 + threadIdx.x;   // i = (b*64+n)*4+f
    if (i < BB * NN * FF) {
        int f = i & 3, bn = i >> 2;
        x0[i] = scrub(inp[(size_t)(bn * TT) * FF + f]);   // inputs[b][n][0][f]
    }
}

static int find_input(const int* in_sizes, int n_in, int want, unsigned char* used, int dflt) {
    if (dflt >= 0 && dflt < n_in && in_sizes[dflt] == want && !used[dflt]) { used[dflt] = 1; return dflt; }
    for (int i = 0; i < n_in; ++i)
        if (!used[i] && in_sizes[i] == want) { used[i] = 1; return i; }
    return dflt;
}

extern "C" void kernel_launch(void* const* d_in, const int* in_sizes, int n_in,
                              void* d_out, int out_size, void* d_ws, size_t ws_size,
                              hipStream_t stream)
{
    unsigned char used[64] = {0};
    int iInp = find_input(in_sizes, n_in, BB*NN*TT*FF, used, 0);
    int iEdg = find_input(in_sizes, n_in, BB*EE*KK,    used, 1);
    (void)find_input(in_sizes, n_in, EE*NN, used, 2);              // rel_rec (unused)
    (void)find_input(in_sizes, n_in, EE*NN, used, 3);              // rel_send (unused)
    int iW1  = find_input(in_sizes, n_in, KK*8*256,  used, 4);
    int ib1  = find_input(in_sizes, n_in, KK*256,    used, 5);
    int iW2  = find_input(in_sizes, n_in, KK*256*256,used, 6);
    int ib2  = find_input(in_sizes, n_in, KK*256,    used, 7);
    int iWo1 = find_input(in_sizes, n_in, 260*256,   used, 8);
    int ibo1 = find_input(in_sizes, n_in, 256,       used, 9);
    int iWo2 = find_input(in_sizes, n_in, 256*256,   used, 10);
    int ibo2 = find_input(in_sizes, n_in, 256,       used, 11);
    int iWo3 = find_input(in_sizes, n_in, 256*4,     used, 12);
    int ibo3 = find_input(in_sizes, n_in, 4,         used, 13);
    int iTs  = find_input(in_sizes, n_in, TT,        used, 14);
    (void)find_input(in_sizes, n_in, 1, used, 15);                 // pred_steps
    int iSc  = find_input(in_sizes, n_in, 1,         used, 16);    // scale

    const float* inputs = (const float*)d_in[iInp];
    const float* edges  = (const float*)d_in[iEdg];
    const float* W1  = (const float*)d_in[iW1];
    const float* b1  = (const float*)d_in[ib1];
    const float* W2  = (const float*)d_in[iW2];
    const float* b2  = (const float*)d_in[ib2];
    const float* Wo1 = (const float*)d_in[iWo1];
    const float* bo1 = (const float*)d_in[ibo1];
    const float* Wo2 = (const float*)d_in[iWo2];
    const float* bo2 = (const float*)d_in[ibo2];
    const float* Wo3 = (const float*)d_in[iWo3];
    const float* bo3 = (const float*)d_in[ibo3];
    const float* ts  = (const float*)d_in[iTs];
    const void*  scp = d_in[iSc];

    char* ws = (char*)d_ws;
    _Float16* W2F = (_Float16*)ws;                     // 262144 B
    float* xA = (float*)(ws + 262144);
    float* xB = (float*)(ws + 262144 + 1 * 32768);
    float* k1 = (float*)(ws + 262144 + 2 * 32768);
    float* k2 = (float*)(ws + 262144 + 3 * 32768);
    float* k3 = (float*)(ws + 262144 + 4 * 32768);

    float* outp = (float*)d_out;   // f32 output

    (void)hipFuncSetAttribute((const void*)stage_kernel,
        hipFuncAttributeMaxDynamicSharedMemorySize, SMEM_BYTES);

    swizzle_w2<<<dim3(512), dim3(256), 0, stream>>>(W2, W2F);
    init_x<<<dim3(32), dim3(256), 0, stream>>>(inputs, xA);

    float* xc = xA;
    float* xn = xB;
    for (int step = 0; step < NSTEP; ++step) {
        stage_kernel<<<dim3(1024), dim3(256), SMEM_BYTES, stream>>>(0, step,
            edges, W1, b1, W2F, b2, Wo1, bo1, Wo2, bo2, Wo3, bo3, ts, scp,
            xc, xc, k1, k1, k2, k3, xn, outp);
        stage_kernel<<<dim3(1024), dim3(256), SMEM_BYTES, stream>>>(1, step,
            edges, W1, b1, W2F, b2, Wo1, bo1, Wo2, bo2, Wo3, bo3, ts, scp,
            xc, k1, k2, k1, k2, k3, xn, outp);
        stage_kernel<<<dim3(1024), dim3(256), SMEM_BYTES, stream>>>(2, step,
            edges, W1, b1, W2F, b2, Wo1, bo1, Wo2, bo2, Wo3, bo3, ts, scp,
            xc, k2, k3, k1, k2, k3, xn, outp);
        stage_kernel<<<dim3(1024), dim3(256), SMEM_BYTES, stream>>>(3, step,
            edges, W1, b1, W2F, b2, Wo1, bo1, Wo2, bo2, Wo3, bo3, ts, scp,
            xc, k3, k3 /*unused*/, k1, k2, k3, xn, outp);
        float* t = xc; xc = xn; xn = t;
    }
}